// Round 4
// baseline (1872.813 us; speedup 1.0000x reference)
//
#include <hip/hip_runtime.h>

#define NN 100000
#define NE 3200000
#define DD 64

constexpr int ELEMS = NN * DD;   // 6,400,000

// ---------------- Threefry-2x32, key = (0, 42), 20 rounds ----------------
__device__ __forceinline__ void threefry2x32_0_42(unsigned int c0, unsigned int c1,
                                                  unsigned int& o0, unsigned int& o1) {
  const unsigned int ks0 = 0u;
  const unsigned int ks1 = 42u;
  const unsigned int ks2 = ks0 ^ ks1 ^ 0x1BD11BDAu;
  unsigned int x0 = c0 + ks0;
  unsigned int x1 = c1 + ks1;
#define TF_R(r) { x0 += x1; x1 = (x1 << (r)) | (x1 >> (32 - (r))); x1 ^= x0; }
  TF_R(13) TF_R(15) TF_R(26) TF_R(6)
  x0 += ks1; x1 += ks2 + 1u;
  TF_R(17) TF_R(29) TF_R(16) TF_R(24)
  x0 += ks2; x1 += ks0 + 2u;
  TF_R(13) TF_R(15) TF_R(26) TF_R(6)
  x0 += ks0; x1 += ks1 + 3u;
  TF_R(17) TF_R(29) TF_R(16) TF_R(24)
  x0 += ks1; x1 += ks2 + 4u;
  TF_R(13) TF_R(15) TF_R(26) TF_R(6)
  x0 += ks2; x1 += ks0 + 5u;
#undef TF_R
  o0 = x0; o1 = x1;
}

__device__ __forceinline__ bool keep_from_bits(unsigned int bits) {
  // jax.random.uniform f32: u = bitcast((bits>>9)|0x3f800000) - 1.0f ; keep = u < 0.9f
  float f = __uint_as_float((bits >> 9) | 0x3f800000u) - 1.0f;
  return f < 0.9f;
}

// ---------------- Kernel A: h = sign(x) (== sign(tanh x)); h0d = tanh(x) in f64 ----------------
__global__ void k_tanh_sign(const float* __restrict__ x,
                            float* __restrict__ h_out,
                            double* __restrict__ h0d) {
  int i = blockIdx.x * blockDim.x + threadIdx.x;
  if (i >= ELEMS) return;
  float xv = x[i];
  h0d[i] = tanh((double)xv);
  h_out[i] = (xv > 0.0f) ? 1.0f : ((xv < 0.0f) ? -1.0f : 0.0f);
}

// ---------------- Kernel B: layer-1 edge scatter (f64 atomics) ----------------
// 64 lanes = one edge's 64 features (coalesced 512B row ops)
__global__ void k_scatter_f64(const int* __restrict__ src,
                              const int* __restrict__ dst,
                              const double* __restrict__ h0d,
                              double* __restrict__ aggd) {
  long long tid = (long long)blockIdx.x * blockDim.x + threadIdx.x;
  int e = (int)(tid >> 6);
  int f = (int)(tid & 63);
  if (e >= NE) return;
  int s = src[e];
  int d = dst[e];
  unsafeAtomicAdd(&aggd[d * DD + f], h0d[s * DD + f]);
}

// ---------------- Kernel C: h1 = sign(agg1 + self) as int8 ----------------
__global__ void k_sign_layer1(const double* __restrict__ aggd,
                              const double* __restrict__ h0d,
                              signed char* __restrict__ h1) {
  int i = blockIdx.x * blockDim.x + threadIdx.x;
  if (i >= ELEMS) return;
  double v = aggd[i] + h0d[i];  // self-loop contribution
  h1[i] = (v > 0.0) ? 1 : ((v < 0.0) ? -1 : 0);
}

// ---------------- Kernel D: layer-2 edge scatter (int32 atomics, exact) ----------------
__global__ void k_scatter_i8(const int* __restrict__ src,
                             const int* __restrict__ dst,
                             const signed char* __restrict__ h1,
                             int* __restrict__ agg2) {
  long long tid = (long long)blockIdx.x * blockDim.x + threadIdx.x;
  int e = (int)(tid >> 6);
  int f = (int)(tid & 63);
  if (e >= NE) return;
  int s = src[e];
  int d = dst[e];
  atomicAdd(&agg2[d * DD + f], (int)h1[s * DD + f]);
}

// ---------------- Kernel E: self-loop + sign + PARTITIONABLE threefry dropout ----------------
// jax_threefry_partitionable=True (default since JAX 0.5): per element i,
// (x1,x2) = threefry2x32(key, (i>>32, i&0xffffffff)); bits32 = x1 ^ x2.
__global__ void k_final(const int* __restrict__ agg2,
                        const signed char* __restrict__ h1,
                        float* __restrict__ out2) {
  int i = blockIdx.x * blockDim.x + threadIdx.x;
  if (i >= ELEMS) return;
  int t = agg2[i] + (int)h1[i];
  float s = (t > 0) ? 1.0f : ((t < 0) ? -1.0f : 0.0f);
  unsigned int o0, o1;
  threefry2x32_0_42(0u, (unsigned int)i, o0, o1);
  unsigned int bits = o0 ^ o1;
  const float inv_keep = 1.0f / 0.9f;  // f32, same as ref's /0.9f for |h2|=1
  out2[i] = keep_from_bits(bits) ? s * inv_keep : 0.0f;
}

extern "C" void kernel_launch(void* const* d_in, const int* in_sizes, int n_in,
                              void* d_out, int out_size, void* d_ws, size_t ws_size,
                              hipStream_t stream) {
  const float* x  = (const float*)d_in[0];
  const int*   ei = (const int*)d_in[1];   // harness converts int64 -> int32
  const int*   src = ei;                   // edge_index[0]
  const int*   dst = ei + NE;              // edge_index[1]

  float* out_h  = (float*)d_out;           // output 0: h    [ELEMS]
  float* out_h2 = (float*)d_out + ELEMS;   // output 1: h_2  [ELEMS]

  char* ws = (char*)d_ws;
  double*      h0d  = (double*)ws;                              // 51.2 MB @ 0
  double*      aggd = (double*)(ws + ((size_t)52 << 20));       // 51.2 MB @ 52MB
  signed char* h1   = (signed char*)(ws + ((size_t)104 << 20)); // 6.4 MB @ 104MB
  int*         agg2 = (int*)aggd;                               // reuse (25.6 MB)

  const int B = 256;

  // zero layer-1 accumulator (ws is poisoned 0xAA before every launch)
  (void)hipMemsetAsync(aggd, 0, (size_t)ELEMS * sizeof(double), stream);

  k_tanh_sign<<<(ELEMS + B - 1) / B, B, 0, stream>>>(x, out_h, h0d);

  k_scatter_f64<<<(int)(((long long)NE * 64 + B - 1) / B), B, 0, stream>>>(src, dst, h0d, aggd);

  k_sign_layer1<<<(ELEMS + B - 1) / B, B, 0, stream>>>(aggd, h0d, h1);

  // zero layer-2 accumulator (stream-ordered after k_sign_layer1 consumed aggd)
  (void)hipMemsetAsync(agg2, 0, (size_t)ELEMS * sizeof(int), stream);

  k_scatter_i8<<<(int)(((long long)NE * 64 + B - 1) / B), B, 0, stream>>>(src, dst, h1, agg2);

  k_final<<<(ELEMS + B - 1) / B, B, 0, stream>>>(agg2, h1, out_h2);
}

// Round 5
// 699.002 us; speedup vs baseline: 2.6793x; 2.6793x over previous
//
#include <hip/hip_runtime.h>

#define NN 100000
#define NE 3200000
#define DD 64

constexpr int ELEMS = NN * DD;         // 6,400,000
constexpr int NB    = (NN + 1023) / 1024; // 98 scan blocks

// ---------------- Threefry-2x32, key = (0, 42), 20 rounds ----------------
__device__ __forceinline__ void threefry2x32_0_42(unsigned int c0, unsigned int c1,
                                                  unsigned int& o0, unsigned int& o1) {
  const unsigned int ks0 = 0u;
  const unsigned int ks1 = 42u;
  const unsigned int ks2 = ks0 ^ ks1 ^ 0x1BD11BDAu;
  unsigned int x0 = c0 + ks0;
  unsigned int x1 = c1 + ks1;
#define TF_R(r) { x0 += x1; x1 = (x1 << (r)) | (x1 >> (32 - (r))); x1 ^= x0; }
  TF_R(13) TF_R(15) TF_R(26) TF_R(6)
  x0 += ks1; x1 += ks2 + 1u;
  TF_R(17) TF_R(29) TF_R(16) TF_R(24)
  x0 += ks2; x1 += ks0 + 2u;
  TF_R(13) TF_R(15) TF_R(26) TF_R(6)
  x0 += ks0; x1 += ks1 + 3u;
  TF_R(17) TF_R(29) TF_R(16) TF_R(24)
  x0 += ks1; x1 += ks2 + 4u;
  TF_R(13) TF_R(15) TF_R(26) TF_R(6)
  x0 += ks2; x1 += ks0 + 5u;
#undef TF_R
  o0 = x0; o1 = x1;
}

__device__ __forceinline__ bool keep_from_bits(unsigned int bits) {
  float f = __uint_as_float((bits >> 9) | 0x3f800000u) - 1.0f;
  return f < 0.9f;
}

// ---------------- A: h = sign(x); h0f = tanh(x) (f32, correctly rounded) ----------------
__global__ void kA(const float* __restrict__ x,
                   float* __restrict__ h_out,
                   float* __restrict__ h0f) {
  int i = blockIdx.x * blockDim.x + threadIdx.x;
  if (i >= ELEMS) return;
  float xv = x[i];
  h0f[i] = (float)tanh((double)xv);
  h_out[i] = (xv > 0.0f) ? 1.0f : ((xv < 0.0f) ? -1.0f : 0.0f);
}

// ---------------- CSR build: histogram over dst ----------------
__global__ void k_hist(const int* __restrict__ dst, int* __restrict__ deg) {
  int e = blockIdx.x * blockDim.x + threadIdx.x;
  if (e >= NE) return;
  atomicAdd(&deg[dst[e]], 1);
}

// ---------------- scan step 1: per-block inclusive scan (1024) ----------------
__global__ void k_scan1(const int* __restrict__ deg,
                        int* __restrict__ tmp, int* __restrict__ bsum) {
  __shared__ int s[1024];
  int t = threadIdx.x;
  int i = blockIdx.x * 1024 + t;
  s[t] = (i < NN) ? deg[i] : 0;
  __syncthreads();
  for (int off = 1; off < 1024; off <<= 1) {
    int add = (t >= off) ? s[t - off] : 0;
    __syncthreads();
    s[t] += add;
    __syncthreads();
  }
  if (i < NN) tmp[i] = s[t];
  if (t == 1023) bsum[blockIdx.x] = s[t];
}

// ---------------- scan step 2: exclusive-scan the 98 block sums ----------------
__global__ void k_scan2(int* __restrict__ bsum) {
  if (blockIdx.x == 0 && threadIdx.x == 0) {
    int run = 0;
    for (int b = 0; b < NB; ++b) { int v = bsum[b]; bsum[b] = run; run += v; }
  }
}

// ---------------- scan step 3: rowptr + cursor ----------------
__global__ void k_scan3(const int* __restrict__ tmp, const int* __restrict__ bsum,
                        int* __restrict__ rowptr, int* __restrict__ cursor) {
  int t = threadIdx.x;
  int i = blockIdx.x * 1024 + t;
  if (i >= NN) return;
  int off = bsum[blockIdx.x];
  rowptr[i + 1] = tmp[i] + off;
  cursor[i] = (t == 0) ? off : tmp[i - 1] + off;
  if (i == 0) rowptr[0] = 0;
}

// ---------------- CSR fill: csr_src grouped by dst ----------------
__global__ void k_fill(const int* __restrict__ src, const int* __restrict__ dst,
                       int* __restrict__ cursor, int* __restrict__ csr_src) {
  int e = blockIdx.x * blockDim.x + threadIdx.x;
  if (e >= NE) return;
  int d = dst[e];
  int pos = atomicAdd(&cursor[d], 1);
  csr_src[pos] = src[e];
}

// ---------------- G1: per-node gather, exact f64 accumulate, sign -> int8 ----------------
// one 64-lane wave per node; lane = feature
__global__ void k_gather1(const int* __restrict__ rowptr, const int* __restrict__ csr_src,
                          const float* __restrict__ h0f, signed char* __restrict__ h1) {
  int g = blockIdx.x * blockDim.x + threadIdx.x;
  int n = g >> 6;
  int lane = g & 63;
  if (n >= NN) return;
  int beg = rowptr[n], end = rowptr[n + 1];
  double acc = (double)h0f[n * DD + lane];  // self-loop
  int j = beg;
  for (; j + 4 <= end; j += 4) {
    int s0 = csr_src[j], s1 = csr_src[j + 1], s2 = csr_src[j + 2], s3 = csr_src[j + 3];
    float v0 = h0f[s0 * DD + lane];
    float v1 = h0f[s1 * DD + lane];
    float v2 = h0f[s2 * DD + lane];
    float v3 = h0f[s3 * DD + lane];
    acc += (double)v0; acc += (double)v1; acc += (double)v2; acc += (double)v3;
  }
  for (; j < end; ++j) acc += (double)h0f[csr_src[j] * DD + lane];
  h1[n * DD + lane] = (acc > 0.0) ? 1 : ((acc < 0.0) ? -1 : 0);
}

// ---------------- G2: per-node int gather + sign + partitionable-threefry dropout ----------------
__global__ void k_gather2(const int* __restrict__ rowptr, const int* __restrict__ csr_src,
                          const signed char* __restrict__ h1, float* __restrict__ out2) {
  int g = blockIdx.x * blockDim.x + threadIdx.x;
  int n = g >> 6;
  int lane = g & 63;
  if (n >= NN) return;
  int beg = rowptr[n], end = rowptr[n + 1];
  int acc = (int)h1[n * DD + lane];  // self-loop
  int j = beg;
  for (; j + 4 <= end; j += 4) {
    int s0 = csr_src[j], s1 = csr_src[j + 1], s2 = csr_src[j + 2], s3 = csr_src[j + 3];
    acc += (int)h1[s0 * DD + lane] + (int)h1[s1 * DD + lane]
         + (int)h1[s2 * DD + lane] + (int)h1[s3 * DD + lane];
  }
  for (; j < end; ++j) acc += (int)h1[csr_src[j] * DD + lane];

  int i = n * DD + lane;
  float s = (acc > 0) ? 1.0f : ((acc < 0) ? -1.0f : 0.0f);
  unsigned int o0, o1;
  threefry2x32_0_42(0u, (unsigned int)i, o0, o1);
  unsigned int bits = o0 ^ o1;
  const float inv_keep = 1.0f / 0.9f;
  out2[i] = keep_from_bits(bits) ? s * inv_keep : 0.0f;
}

extern "C" void kernel_launch(void* const* d_in, const int* in_sizes, int n_in,
                              void* d_out, int out_size, void* d_ws, size_t ws_size,
                              hipStream_t stream) {
  const float* x   = (const float*)d_in[0];
  const int*   ei  = (const int*)d_in[1];
  const int*   src = ei;        // edge_index[0]
  const int*   dst = ei + NE;   // edge_index[1]

  float* out_h  = (float*)d_out;           // output 0: h    [ELEMS]
  float* out_h2 = (float*)d_out + ELEMS;   // output 1: h_2  [ELEMS]

  char* ws = (char*)d_ws;
  float*       h0f     = (float*)ws;                              // 25.6 MB @ 0
  signed char* h1      = (signed char*)(ws + ((size_t)26 << 20)); // 6.4 MB @ 26M
  int*         deg     = (int*)(ws + ((size_t)33 << 20));         // 400 KB
  int*         tmp     = (int*)(ws + ((size_t)34 << 20));         // 400 KB
  int*         bsum    = (int*)(ws + ((size_t)35 << 20));         // <1 KB
  int*         rowptr  = (int*)(ws + ((size_t)36 << 20));         // 400 KB + 4
  int*         cursor  = (int*)(ws + ((size_t)37 << 20));         // 400 KB
  int*         csr_src = (int*)(ws + ((size_t)38 << 20));         // 12.8 MB

  const int B = 256;
  const int gElems = (ELEMS + B - 1) / B;          // 25000
  const int gEdges = (NE + B - 1) / B;             // 12500

  // deg must be zeroed every call (ws re-poisoned 0xAA)
  (void)hipMemsetAsync(deg, 0, (size_t)NN * sizeof(int), stream);

  kA<<<gElems, B, 0, stream>>>(x, out_h, h0f);

  k_hist<<<gEdges, B, 0, stream>>>(dst, deg);
  k_scan1<<<NB, 1024, 0, stream>>>(deg, tmp, bsum);
  k_scan2<<<1, 64, 0, stream>>>(bsum);
  k_scan3<<<NB, 1024, 0, stream>>>(tmp, bsum, rowptr, cursor);
  k_fill<<<gEdges, B, 0, stream>>>(src, dst, cursor, csr_src);

  k_gather1<<<gElems, B, 0, stream>>>(rowptr, csr_src, h0f, h1);
  k_gather2<<<gElems, B, 0, stream>>>(rowptr, csr_src, h1, out_h2);
}